// Round 6
// baseline (279.914 us; speedup 1.0000x reference)
//
#include <hip/hip_runtime.h>

#define NB 128
#define CC 1024
#define HWP 196
#define HH 14
#define OO 256

typedef unsigned short ushort_t;
typedef __attribute__((ext_vector_type(4))) short short4v;
typedef __attribute__((ext_vector_type(8))) short short8;
typedef __attribute__((ext_vector_type(4))) float float4v;

__device__ __forceinline__ ushort_t f2bf(float v) {
  union { float f; unsigned int u; } c; c.f = v;
  unsigned int u = c.u;
  unsigned int r = (u + 0x7FFFu + ((u >> 16) & 1u)) >> 16;   // RNE
  return (ushort_t)r;
}

// K1: fused (a) partial channel-sum + 512B-row-padded bf16 copy of x,
// (b) weight bf16 cast.
// Reduce: one wave per (n,cg); lanes 0..48 hold float4 (4 consecutive p).
// Component-wise accumulation over c=0..127 ascending — bit-identical per-p
// FP order (medK rank selection is knife-edge sensitive to this order; do NOT
// reorder the c loop). Lanes >=49 sum zeros that are never stored (harmless).
// xb16 rows are 256 ushorts (512 B): lanes 0..55 store 448 contiguous bytes
// (49*8 data + 7*8 zero pad) per row per instr = 7 FULL 64B lines -> no
// partial-line RMW fetch (R4's 51MB-FETCH failure mode). Bytes 448..511 of
// each row are never written and never read.
__global__ __launch_bounds__(256) void k_prep(const float* __restrict__ x,
                                              const float* __restrict__ wmax,
                                              const float* __restrict__ wmed,
                                              float* __restrict__ partial,
                                              ushort_t* __restrict__ wb,
                                              ushort_t* __restrict__ xb16) {
  const int b = blockIdx.x, t = threadIdx.x;
  if (b >= 256) {   // weight cast: 2048 blocks x 256 = 2*OO*CC elements
    int idx = (b - 256) * 256 + t;
    int z = idx >> 18;
    int r = idx & (OO * CC - 1);
    const float* w = z ? wmed : wmax;
    wb[idx] = f2bf(w[r]);
    return;
  }
  const int unit = b * 4 + (t >> 6);     // (n,cg) unit, one per wave
  const int lane = t & 63;
  const int n = unit >> 3, cg = unit & 7;
  const float4* base = (const float4*)(x + ((size_t)n * CC + (size_t)cg * 128) * HWP);
  ushort_t* xo = xb16 + (((size_t)n * CC + (size_t)cg * 128) << 8) + (size_t)lane * 4;
  float4 s = {0.f, 0.f, 0.f, 0.f};
  #pragma unroll 16
  for (int c = 0; c < 128; ++c) {
    float4 v = {0.f, 0.f, 0.f, 0.f};
    if (lane < 49) v = base[c * 49 + lane];
    s.x += v.x; s.y += v.y; s.z += v.z; s.w += v.w;   // per-p sequential order
    if (lane < 56) {
      short4v o;
      o[0] = (short)f2bf(v.x); o[1] = (short)f2bf(v.y);
      o[2] = (short)f2bf(v.z); o[3] = (short)f2bf(v.w);
      *(short4v*)(xo + ((size_t)c << 8)) = o;         // 448B/row, full lines
    }
  }
  if (lane < 49)
    ((float4*)(partial + ((size_t)n * 8 + cg) * HWP))[lane] = s;
}

// K2: per (n,z) block, 512 threads (8 waves) — EXACT R0 structure; the only
// change is the gather source: bf16 from 512B-padded xb16 rows instead of f32
// from 784B x rows. 16 positions span ~4.5 of 6.125 lines per row (vs ~9.3 of
// 12.25 in f32) -> ~4.6K line-transactions/CU (2.1x fewer than R0), and the
// 16K f2bf converts are gone (done in k_prep; values bit-identical).
__global__ __launch_bounds__(512, 2) void k_main(
    const float* __restrict__ partial,
    const ushort_t* __restrict__ wb,
    const ushort_t* __restrict__ xb16,
    const float* __restrict__ g_max, const float* __restrict__ b_max,
    const float* __restrict__ m_max, const float* __restrict__ v_max,
    const float* __restrict__ g_med, const float* __restrict__ b_med,
    const float* __restrict__ m_med, const float* __restrict__ v_med,
    float* __restrict__ out) {
  constexpr int AP = 1032;               // padded row stride (ushorts)
  __shared__ alignas(16) ushort_t A_sh[16 * AP];   // 33 KB
  __shared__ float fre[HWP];
  __shared__ int sc[32];
  __shared__ float Lsh[16][17];
  __shared__ float dinv[16];
  __shared__ float y_sh[16][257];        // 16.4 KB

  const int n = blockIdx.x;
  const int z = blockIdx.y;
  const int t = threadIdx.x;

  // ---- select: fre = sum of 8 partials (sequential); stable ranks ----
  if (t < HWP) {
    float s = 0.f;
    #pragma unroll
    for (int g = 0; g < 8; ++g) s += partial[((size_t)n * 8 + g) * HWP + t];
    fre[t] = s;
  }
  __syncthreads();
  if (t < HWP) {
    float v = fre[t];
    int rank = 0;
    #pragma unroll 4
    for (int q = 0; q < HWP; ++q) {
      float u = fre[q];
      rank += ((u > v) || (u == v && q < t)) ? 1 : 0;
    }
    if (rank < 16) sc[rank] = t;                           // maxK: ranks 0..15
    else if (rank >= 89 && rank < 105) sc[rank - 73] = t;  // medK: ranks 89..104
  }
  __syncthreads();

  if (z == 0 && t < 32) {
    int p = sc[t];
    out[2 * NB * 4096 + n * 32 + t] = (float)(p / HH);            // rows
    out[2 * NB * 4096 + NB * 32 + n * 32 + t] = (float)(p % HH);  // cols
  }

  // ---- gather A (16 x 1024 bf16) from xb16; R0's proven lane map:
  // per wave-instr 4 rows x 16 positions; 32-deep ILP per thread ----
  {
    const int j = t & 15;
    const int g = t >> 4;              // 32 channel-groups of 32
    const int sj = sc[z * 16 + j];
    const ushort_t* xb = xb16 + (((size_t)n * CC + (size_t)g * 32) << 8) + sj;
    ushort_t* arow = &A_sh[j * AP + g * 32];
    #pragma unroll 16
    for (int u = 0; u < 32; ++u) {
      arow[u] = xb[(size_t)u << 8];
    }
  }
  // ---- L matrix ----
  if (t < 256) {
    const int i = t >> 4, j = t & 15;
    int pi = sc[z * 16 + i], pj = sc[z * 16 + j];
    float dr = (float)(pi / HH - pj / HH);
    float dc = (float)(pi % HH - pj % HH);
    Lsh[i][j] = 1.0f / (1.0f + sqrtf(dr * dr + dc * dc));
  }
  __syncthreads();
  if (t < 16) {
    float s = 0.f;
    #pragma unroll
    for (int j = 0; j < 16; ++j) s += Lsh[t][j];
    dinv[t] = rsqrtf(s);
  }

  const int w = t >> 6;                  // 8 waves, 32 output cols each
  const int l = t & 63;
  const int m = l & 15;
  const int quad = l >> 4;

  const ushort_t* Arow = &A_sh[m * AP + quad * 8];
  const ushort_t* B0 = wb + (size_t)z * (OO * CC) + (size_t)(w * 32 + m) * CC + quad * 8;

  float4v acc0 = {0.f, 0.f, 0.f, 0.f};
  float4v acc1 = acc0;

  __syncthreads();   // dinv + A_sh visible

  #pragma unroll 4
  for (int k0 = 0; k0 < CC; k0 += 32) {
    short8 a  = *reinterpret_cast<const short8*>(Arow + k0);
    short8 b0 = *reinterpret_cast<const short8*>(B0 + k0);
    short8 b1 = *reinterpret_cast<const short8*>(B0 + 16 * CC + k0);
    acc0 = __builtin_amdgcn_mfma_f32_16x16x32_bf16(a, b0, acc0, 0, 0, 0);
    acc1 = __builtin_amdgcn_mfma_f32_16x16x32_bf16(a, b1, acc1, 0, 0, 0);
  }

  const float* gp = z ? g_med : g_max;
  const float* bp = z ? b_med : b_max;
  const float* mp = z ? m_med : m_max;
  const float* vp = z ? v_med : v_max;

  // BN + ReLU; scatter C-layout (col=lane&15, row=quad*4+reg) to LDS
  #pragma unroll
  for (int tt = 0; tt < 2; ++tt) {
    float4v av = tt ? acc1 : acc0;
    int o = w * 32 + tt * 16 + m;
    float scale = gp[o] * rsqrtf(vp[o] + 1e-5f);
    float shift = bp[o] - mp[o] * scale;
    #pragma unroll
    for (int r = 0; r < 4; ++r) {
      int j = quad * 4 + r;
      float y = av[r] * scale + shift;
      y = fmaxf(y, 0.f);
      y_sh[j][o] = y * dinv[j];
    }
  }
  __syncthreads();

  // out[n,z,i,o] = dinv_i * sum_j L[i][j] * (dinv_j * y[j][o])
  // 512 threads: o = t&255, half-i-range per t>>8
  {
    const int o = t & 255;
    const int ih = (t >> 8) * 8;
    float yp[16];
    #pragma unroll
    for (int j = 0; j < 16; ++j) yp[j] = y_sh[j][o];
    float* ob = out + (size_t)z * (NB * 4096) + (size_t)n * 4096 + o;
    #pragma unroll
    for (int i2 = 0; i2 < 8; ++i2) {
      const int i = ih + i2;
      float s = 0.f;
      #pragma unroll
      for (int j = 0; j < 16; ++j) s = fmaf(Lsh[i][j], yp[j], s);
      ob[(size_t)i * OO] = s * dinv[i];
    }
  }
}

extern "C" void kernel_launch(void* const* d_in, const int* in_sizes, int n_in,
                              void* d_out, int out_size, void* d_ws, size_t ws_size,
                              hipStream_t stream) {
  const float* x     = (const float*)d_in[0];
  const float* w_max = (const float*)d_in[2];
  const float* g_max = (const float*)d_in[3];
  const float* b_max = (const float*)d_in[4];
  const float* m_max = (const float*)d_in[5];
  const float* v_max = (const float*)d_in[6];
  const float* w_med = (const float*)d_in[7];
  const float* g_med = (const float*)d_in[8];
  const float* b_med = (const float*)d_in[9];
  const float* m_med = (const float*)d_in[10];
  const float* v_med = (const float*)d_in[11];
  float* out = (float*)d_out;

  float* ws_f = (float*)d_ws;
  float* partial  = ws_f;                        // 128*8*196 floats   (0.80 MB)
  ushort_t* wb    = (ushort_t*)(ws_f + 200704);  // 2*256*1024 ushorts (1 MB)
  ushort_t* xb16  = wb + 2 * OO * CC;            // 131072 rows x 512B (67 MB)
                                                 // (offset 1851392 B = 512-B aligned)

  k_prep<<<dim3(256 + 2048), 256, 0, stream>>>(x, w_max, w_med, partial, wb, xb16);
  k_main<<<dim3(NB, 2), 512, 0, stream>>>(partial, wb, xb16,
                                          g_max, b_max, m_max, v_max,
                                          g_med, b_med, m_med, v_med, out);
}

// Round 7
// 232.988 us; speedup vs baseline: 1.2014x; 1.2014x over previous
//
#include <hip/hip_runtime.h>

#define NB 128
#define CC 1024
#define HWP 196
#define HH 14
#define OO 256

typedef unsigned short ushort_t;
typedef __attribute__((ext_vector_type(4))) short short4v;
typedef __attribute__((ext_vector_type(8))) short short8;
typedef __attribute__((ext_vector_type(4))) float float4v;

__device__ __forceinline__ ushort_t f2bf(float v) {
  union { float f; unsigned int u; } c; c.f = v;
  unsigned int u = c.u;
  unsigned int r = (u + 0x7FFFu + ((u >> 16) & 1u)) >> 16;   // RNE
  return (ushort_t)r;
}

// K1: three roles, interleaved per-n for L3 locality (10 role-blocks per n,
// then 2048 cast blocks):
//   rr<2 : reduce — BYTE-IDENTICAL to the proven R0 reduce. b_equiv=nn*2+rr
//          reproduces R0's block->unit mapping exactly (unit=b*4+(t>>6)).
//          Component-wise accumulation over c ascending; do NOT reorder.
//   rr>=2: bf16 copy of x into 512B-padded rows. Separate blocks => 6-8
//          blocks/CU of TLP (the R4/R6 fused version ran this at 1 wave/SIMD
//          inside the 256 reduce blocks and died on serialized vmcnt chains).
//          Full-wave coalesced float4 reads, one 448B coalesced store per row
//          (49*8B data + 7*8B zero pad); bytes 448..511 never written/read.
//   cast : weight bf16 cast (trivial, scheduled last).
__global__ __launch_bounds__(256) void k_prep(const float* __restrict__ x,
                                              const float* __restrict__ wmax,
                                              const float* __restrict__ wmed,
                                              float* __restrict__ partial,
                                              ushort_t* __restrict__ wb,
                                              ushort_t* __restrict__ xb16) {
  const int bid = blockIdx.x, t = threadIdx.x;

  if (bid >= 1280) {   // ---- weight cast: 2048 blocks x 256 = 2*OO*CC ----
    int idx = (bid - 1280) * 256 + t;
    int z = idx >> 18;
    int r = idx & (OO * CC - 1);
    const float* w = z ? wmed : wmax;
    wb[idx] = f2bf(w[r]);
    return;
  }

  const int nn = bid / 10, rr = bid % 10;

  if (rr >= 2) {   // ---- copy role: 8 blocks/n, 128 rows each ----
    const int cg = rr - 2;
    const int w = t >> 6, lane = t & 63;
    const int row0 = cg * 128 + w * 32;          // 32 rows per wave
    const float4* xb = (const float4*)(x + ((size_t)nn * CC + row0) * HWP);
    ushort_t* xo = xb16 + (((size_t)nn * CC + row0) << 8) + (size_t)lane * 4;
    #pragma unroll 4
    for (int r = 0; r < 32; ++r) {
      float4 v = {0.f, 0.f, 0.f, 0.f};
      if (lane < 49) v = xb[r * 49 + lane];
      short4v o;
      o[0] = (short)f2bf(v.x); o[1] = (short)f2bf(v.y);
      o[2] = (short)f2bf(v.z); o[3] = (short)f2bf(v.w);
      if (lane < 56) *(short4v*)(xo + ((size_t)r << 8)) = o;  // 448B/row
    }
    return;
  }

  // ---- reduce role: EXACT R0 code; b_equiv in [0,256) ----
  const int b_equiv = nn * 2 + rr;
  const int unit = b_equiv * 4 + (t >> 6);   // (n,cg) unit, one per wave
  const int lane = t & 63;
  if (lane >= 49) return;                    // 49 float4s cover 196 floats
  const int n = unit >> 3, cg = unit & 7;
  const float4* base = (const float4*)(x + ((size_t)n * CC + (size_t)cg * 128) * HWP);
  float4 s = {0.f, 0.f, 0.f, 0.f};
  #pragma unroll 16
  for (int c = 0; c < 128; ++c) {
    float4 v = base[c * 49 + lane];
    s.x += v.x; s.y += v.y; s.z += v.z; s.w += v.w;   // per-p sequential order
  }
  ((float4*)(partial + ((size_t)n * 8 + cg) * HWP))[lane] = s;
}

// K2 (EXACT R6 version, measured ~45us): per (n,z) block, 512 threads.
// Gather source is bf16 512B-padded xb16 rows: 16 positions span ~5.8 of 7
// lines per row (vs ~9.3 of 12.25 for f32 x) -> ~0.69x line transactions,
// and all 16K f2bf converts live in k_prep (bit-identical values).
__global__ __launch_bounds__(512, 2) void k_main(
    const float* __restrict__ partial,
    const ushort_t* __restrict__ wb,
    const ushort_t* __restrict__ xb16,
    const float* __restrict__ g_max, const float* __restrict__ b_max,
    const float* __restrict__ m_max, const float* __restrict__ v_max,
    const float* __restrict__ g_med, const float* __restrict__ b_med,
    const float* __restrict__ m_med, const float* __restrict__ v_med,
    float* __restrict__ out) {
  constexpr int AP = 1032;               // padded row stride (ushorts)
  __shared__ alignas(16) ushort_t A_sh[16 * AP];   // 33 KB
  __shared__ float fre[HWP];
  __shared__ int sc[32];
  __shared__ float Lsh[16][17];
  __shared__ float dinv[16];
  __shared__ float y_sh[16][257];        // 16.4 KB

  const int n = blockIdx.x;
  const int z = blockIdx.y;
  const int t = threadIdx.x;

  // ---- select: fre = sum of 8 partials (sequential); stable ranks ----
  if (t < HWP) {
    float s = 0.f;
    #pragma unroll
    for (int g = 0; g < 8; ++g) s += partial[((size_t)n * 8 + g) * HWP + t];
    fre[t] = s;
  }
  __syncthreads();
  if (t < HWP) {
    float v = fre[t];
    int rank = 0;
    #pragma unroll 4
    for (int q = 0; q < HWP; ++q) {
      float u = fre[q];
      rank += ((u > v) || (u == v && q < t)) ? 1 : 0;
    }
    if (rank < 16) sc[rank] = t;                           // maxK: ranks 0..15
    else if (rank >= 89 && rank < 105) sc[rank - 73] = t;  // medK: ranks 89..104
  }
  __syncthreads();

  if (z == 0 && t < 32) {
    int p = sc[t];
    out[2 * NB * 4096 + n * 32 + t] = (float)(p / HH);            // rows
    out[2 * NB * 4096 + NB * 32 + n * 32 + t] = (float)(p % HH);  // cols
  }

  // ---- gather A (16 x 1024 bf16) from xb16; R0's proven lane map:
  // per wave-instr 4 rows x 16 positions; 32-deep ILP per thread ----
  {
    const int j = t & 15;
    const int g = t >> 4;              // 32 channel-groups of 32
    const int sj = sc[z * 16 + j];
    const ushort_t* xb = xb16 + (((size_t)n * CC + (size_t)g * 32) << 8) + sj;
    ushort_t* arow = &A_sh[j * AP + g * 32];
    #pragma unroll 16
    for (int u = 0; u < 32; ++u) {
      arow[u] = xb[(size_t)u << 8];
    }
  }
  // ---- L matrix ----
  if (t < 256) {
    const int i = t >> 4, j = t & 15;
    int pi = sc[z * 16 + i], pj = sc[z * 16 + j];
    float dr = (float)(pi / HH - pj / HH);
    float dc = (float)(pi % HH - pj % HH);
    Lsh[i][j] = 1.0f / (1.0f + sqrtf(dr * dr + dc * dc));
  }
  __syncthreads();
  if (t < 16) {
    float s = 0.f;
    #pragma unroll
    for (int j = 0; j < 16; ++j) s += Lsh[t][j];
    dinv[t] = rsqrtf(s);
  }

  const int w = t >> 6;                  // 8 waves, 32 output cols each
  const int l = t & 63;
  const int m = l & 15;
  const int quad = l >> 4;

  const ushort_t* Arow = &A_sh[m * AP + quad * 8];
  const ushort_t* B0 = wb + (size_t)z * (OO * CC) + (size_t)(w * 32 + m) * CC + quad * 8;

  float4v acc0 = {0.f, 0.f, 0.f, 0.f};
  float4v acc1 = acc0;

  __syncthreads();   // dinv + A_sh visible

  #pragma unroll 4
  for (int k0 = 0; k0 < CC; k0 += 32) {
    short8 a  = *reinterpret_cast<const short8*>(Arow + k0);
    short8 b0 = *reinterpret_cast<const short8*>(B0 + k0);
    short8 b1 = *reinterpret_cast<const short8*>(B0 + 16 * CC + k0);
    acc0 = __builtin_amdgcn_mfma_f32_16x16x32_bf16(a, b0, acc0, 0, 0, 0);
    acc1 = __builtin_amdgcn_mfma_f32_16x16x32_bf16(a, b1, acc1, 0, 0, 0);
  }

  const float* gp = z ? g_med : g_max;
  const float* bp = z ? b_med : b_max;
  const float* mp = z ? m_med : m_max;
  const float* vp = z ? v_med : v_max;

  // BN + ReLU; scatter C-layout (col=lane&15, row=quad*4+reg) to LDS
  #pragma unroll
  for (int tt = 0; tt < 2; ++tt) {
    float4v av = tt ? acc1 : acc0;
    int o = w * 32 + tt * 16 + m;
    float scale = gp[o] * rsqrtf(vp[o] + 1e-5f);
    float shift = bp[o] - mp[o] * scale;
    #pragma unroll
    for (int r = 0; r < 4; ++r) {
      int j = quad * 4 + r;
      float y = av[r] * scale + shift;
      y = fmaxf(y, 0.f);
      y_sh[j][o] = y * dinv[j];
    }
  }
  __syncthreads();

  // out[n,z,i,o] = dinv_i * sum_j L[i][j] * (dinv_j * y[j][o])
  // 512 threads: o = t&255, half-i-range per t>>8
  {
    const int o = t & 255;
    const int ih = (t >> 8) * 8;
    float yp[16];
    #pragma unroll
    for (int j = 0; j < 16; ++j) yp[j] = y_sh[j][o];
    float* ob = out + (size_t)z * (NB * 4096) + (size_t)n * 4096 + o;
    #pragma unroll
    for (int i2 = 0; i2 < 8; ++i2) {
      const int i = ih + i2;
      float s = 0.f;
      #pragma unroll
      for (int j = 0; j < 16; ++j) s = fmaf(Lsh[i][j], yp[j], s);
      ob[(size_t)i * OO] = s * dinv[i];
    }
  }
}

extern "C" void kernel_launch(void* const* d_in, const int* in_sizes, int n_in,
                              void* d_out, int out_size, void* d_ws, size_t ws_size,
                              hipStream_t stream) {
  const float* x     = (const float*)d_in[0];
  const float* w_max = (const float*)d_in[2];
  const float* g_max = (const float*)d_in[3];
  const float* b_max = (const float*)d_in[4];
  const float* m_max = (const float*)d_in[5];
  const float* v_max = (const float*)d_in[6];
  const float* w_med = (const float*)d_in[7];
  const float* g_med = (const float*)d_in[8];
  const float* b_med = (const float*)d_in[9];
  const float* m_med = (const float*)d_in[10];
  const float* v_med = (const float*)d_in[11];
  float* out = (float*)d_out;

  float* ws_f = (float*)d_ws;
  float* partial  = ws_f;                        // 128*8*196 floats   (0.80 MB)
  ushort_t* wb    = (ushort_t*)(ws_f + 200704);  // 2*256*1024 ushorts (1 MB)
  ushort_t* xb16  = wb + 2 * OO * CC;            // 131072 rows x 512B (67 MB)
                                                 // (offset 1851392 B, 512-B aligned)

  k_prep<<<dim3(1280 + 2048), 256, 0, stream>>>(x, w_max, w_med, partial, wb, xb16);
  k_main<<<dim3(NB, 2), 512, 0, stream>>>(partial, wb, xb16,
                                          g_max, b_max, m_max, v_max,
                                          g_med, b_med, m_med, v_med, out);
}

// Round 8
// 212.121 us; speedup vs baseline: 1.3196x; 1.0984x over previous
//
#include <hip/hip_runtime.h>

#define NB 128
#define CC 1024
#define HWP 196
#define HH 14
#define OO 256

typedef unsigned short ushort_t;
typedef __attribute__((ext_vector_type(8))) short short8;
typedef __attribute__((ext_vector_type(4))) float float4v;

__device__ __forceinline__ ushort_t f2bf(float v) {
  union { float f; unsigned int u; } c; c.f = v;
  unsigned int u = c.u;
  unsigned int r = (u + 0x7FFFu + ((u >> 16) & 1u)) >> 16;   // RNE
  return (ushort_t)r;
}

// K1: read-x-ONCE fused reduce+bf16-copy, parallelized over p (not c).
// Blocks 0..1023: one block per (n,cg) unit; thread t = position p (t<196).
//   Scalar chain s += x[n][cg*128+c][p], c=0..127 ASCENDING — the per-p FP
//   add sequence is bit-identical to R0's float4 component-wise reduce (medK
//   rank selection is knife-edge sensitive; do NOT reorder / re-split c).
//   Each iteration also stores f2bf(v) to unpadded xb16[n][c][p] (dense 2B
//   stores, 128B/wave-instr segments; partial-line writes carry no RMW
//   penalty — measured R6: padded full-line stores gave identical FETCH).
//   4x the blocks of R0's reduce (1024, 4 waves each) -> 16 waves/CU TLP.
// Blocks 1024..1279: vectorized weight cast (8 elems/thread, short8 stores).
__global__ __launch_bounds__(256) void k_prep(const float* __restrict__ x,
                                              const float* __restrict__ wmax,
                                              const float* __restrict__ wmed,
                                              float* __restrict__ partial,
                                              ushort_t* __restrict__ wb,
                                              ushort_t* __restrict__ xb16) {
  const int bid = blockIdx.x, t = threadIdx.x;

  if (bid >= 1024) {   // ---- weight cast: 256 blocks x 256 thr x 8 elems ----
    int base = ((bid - 1024) * 256 + t) * 8;
    int z = base >> 18;                    // OO*CC = 2^18
    int r = base & (OO * CC - 1);
    const float* w = z ? wmed : wmax;
    short8 o;
    #pragma unroll
    for (int q = 0; q < 8; ++q) o[q] = (short)f2bf(w[r + q]);
    *(short8*)(wb + base) = o;
    return;
  }

  // ---- fused reduce + copy: unit (n,cg), thread-per-p ----
  const int n = bid >> 3, cg = bid & 7;
  if (t >= HWP) return;
  const float* xp = x + ((size_t)n * CC + (size_t)cg * 128) * HWP + t;
  ushort_t* xo = xb16 + ((size_t)n * CC + (size_t)cg * 128) * HWP + t;
  float s = 0.f;
  #pragma unroll 8
  for (int c = 0; c < 128; ++c) {
    float v = xp[(size_t)c * HWP];
    s += v;                                // per-p sequential c-ascending
    xo[(size_t)c * HWP] = f2bf(v);
  }
  partial[((size_t)n * 8 + cg) * HWP + t] = s;
}

// K2 (R7-proven structure, ~42us): per (n,z) block, 512 threads (8 waves).
// Gather source: unpadded 392B bf16 rows of xb16 (16 positions span ~5 of
// 6.125 lines/row vs ~9.3 of 12.25 for f32 -> ~0.55x line transactions of
// R0), and all 16K f2bf converts live in k_prep (bit-identical values).
__global__ __launch_bounds__(512, 2) void k_main(
    const float* __restrict__ partial,
    const ushort_t* __restrict__ wb,
    const ushort_t* __restrict__ xb16,
    const float* __restrict__ g_max, const float* __restrict__ b_max,
    const float* __restrict__ m_max, const float* __restrict__ v_max,
    const float* __restrict__ g_med, const float* __restrict__ b_med,
    const float* __restrict__ m_med, const float* __restrict__ v_med,
    float* __restrict__ out) {
  constexpr int AP = 1032;               // padded row stride (ushorts)
  __shared__ alignas(16) ushort_t A_sh[16 * AP];   // 33 KB
  __shared__ float fre[HWP];
  __shared__ int sc[32];
  __shared__ float Lsh[16][17];
  __shared__ float dinv[16];
  __shared__ float y_sh[16][257];        // 16.4 KB

  const int n = blockIdx.x;
  const int z = blockIdx.y;
  const int t = threadIdx.x;

  // ---- select: fre = sum of 8 partials (sequential); stable ranks ----
  if (t < HWP) {
    float s = 0.f;
    #pragma unroll
    for (int g = 0; g < 8; ++g) s += partial[((size_t)n * 8 + g) * HWP + t];
    fre[t] = s;
  }
  __syncthreads();
  if (t < HWP) {
    float v = fre[t];
    int rank = 0;
    #pragma unroll 4
    for (int q = 0; q < HWP; ++q) {
      float u = fre[q];
      rank += ((u > v) || (u == v && q < t)) ? 1 : 0;
    }
    if (rank < 16) sc[rank] = t;                           // maxK: ranks 0..15
    else if (rank >= 89 && rank < 105) sc[rank - 73] = t;  // medK: ranks 89..104
  }
  __syncthreads();

  if (z == 0 && t < 32) {
    int p = sc[t];
    out[2 * NB * 4096 + n * 32 + t] = (float)(p / HH);            // rows
    out[2 * NB * 4096 + NB * 32 + n * 32 + t] = (float)(p % HH);  // cols
  }

  // ---- gather A (16 x 1024 bf16) from xb16; R0's proven lane map:
  // per wave-instr 4 rows x 16 positions; 32-deep ILP per thread ----
  {
    const int j = t & 15;
    const int g = t >> 4;              // 32 channel-groups of 32
    const int sj = sc[z * 16 + j];
    const ushort_t* xb = xb16 + ((size_t)n * CC + (size_t)g * 32) * HWP + sj;
    ushort_t* arow = &A_sh[j * AP + g * 32];
    #pragma unroll 16
    for (int u = 0; u < 32; ++u) {
      arow[u] = xb[(size_t)u * HWP];
    }
  }
  // ---- L matrix ----
  if (t < 256) {
    const int i = t >> 4, j = t & 15;
    int pi = sc[z * 16 + i], pj = sc[z * 16 + j];
    float dr = (float)(pi / HH - pj / HH);
    float dc = (float)(pi % HH - pj % HH);
    Lsh[i][j] = 1.0f / (1.0f + sqrtf(dr * dr + dc * dc));
  }
  __syncthreads();
  if (t < 16) {
    float s = 0.f;
    #pragma unroll
    for (int j = 0; j < 16; ++j) s += Lsh[t][j];
    dinv[t] = rsqrtf(s);
  }

  const int w = t >> 6;                  // 8 waves, 32 output cols each
  const int l = t & 63;
  const int m = l & 15;
  const int quad = l >> 4;

  const ushort_t* Arow = &A_sh[m * AP + quad * 8];
  const ushort_t* B0 = wb + (size_t)z * (OO * CC) + (size_t)(w * 32 + m) * CC + quad * 8;

  float4v acc0 = {0.f, 0.f, 0.f, 0.f};
  float4v acc1 = acc0;

  __syncthreads();   // dinv + A_sh visible

  #pragma unroll 4
  for (int k0 = 0; k0 < CC; k0 += 32) {
    short8 a  = *reinterpret_cast<const short8*>(Arow + k0);
    short8 b0 = *reinterpret_cast<const short8*>(B0 + k0);
    short8 b1 = *reinterpret_cast<const short8*>(B0 + 16 * CC + k0);
    acc0 = __builtin_amdgcn_mfma_f32_16x16x32_bf16(a, b0, acc0, 0, 0, 0);
    acc1 = __builtin_amdgcn_mfma_f32_16x16x32_bf16(a, b1, acc1, 0, 0, 0);
  }

  const float* gp = z ? g_med : g_max;
  const float* bp = z ? b_med : b_max;
  const float* mp = z ? m_med : m_max;
  const float* vp = z ? v_med : v_max;

  // BN + ReLU; scatter C-layout (col=lane&15, row=quad*4+reg) to LDS
  #pragma unroll
  for (int tt = 0; tt < 2; ++tt) {
    float4v av = tt ? acc1 : acc0;
    int o = w * 32 + tt * 16 + m;
    float scale = gp[o] * rsqrtf(vp[o] + 1e-5f);
    float shift = bp[o] - mp[o] * scale;
    #pragma unroll
    for (int r = 0; r < 4; ++r) {
      int j = quad * 4 + r;
      float y = av[r] * scale + shift;
      y = fmaxf(y, 0.f);
      y_sh[j][o] = y * dinv[j];
    }
  }
  __syncthreads();

  // out[n,z,i,o] = dinv_i * sum_j L[i][j] * (dinv_j * y[j][o])
  // 512 threads: o = t&255, half-i-range per t>>8
  {
    const int o = t & 255;
    const int ih = (t >> 8) * 8;
    float yp[16];
    #pragma unroll
    for (int j = 0; j < 16; ++j) yp[j] = y_sh[j][o];
    float* ob = out + (size_t)z * (NB * 4096) + (size_t)n * 4096 + o;
    #pragma unroll
    for (int i2 = 0; i2 < 8; ++i2) {
      const int i = ih + i2;
      float s = 0.f;
      #pragma unroll
      for (int j = 0; j < 16; ++j) s = fmaf(Lsh[i][j], yp[j], s);
      ob[(size_t)i * OO] = s * dinv[i];
    }
  }
}

extern "C" void kernel_launch(void* const* d_in, const int* in_sizes, int n_in,
                              void* d_out, int out_size, void* d_ws, size_t ws_size,
                              hipStream_t stream) {
  const float* x     = (const float*)d_in[0];
  const float* w_max = (const float*)d_in[2];
  const float* g_max = (const float*)d_in[3];
  const float* b_max = (const float*)d_in[4];
  const float* m_max = (const float*)d_in[5];
  const float* v_max = (const float*)d_in[6];
  const float* w_med = (const float*)d_in[7];
  const float* g_med = (const float*)d_in[8];
  const float* b_med = (const float*)d_in[9];
  const float* m_med = (const float*)d_in[10];
  const float* v_med = (const float*)d_in[11];
  float* out = (float*)d_out;

  float* ws_f = (float*)d_ws;
  float* partial  = ws_f;                        // 128*8*196 floats   (0.80 MB)
  ushort_t* wb    = (ushort_t*)(ws_f + 200704);  // 2*256*1024 ushorts (1 MB)
  ushort_t* xb16  = wb + 2 * OO * CC;            // 128*1024*196 bf16  (51.4 MB)

  k_prep<<<dim3(1024 + 256), 256, 0, stream>>>(x, w_max, w_med, partial, wb, xb16);
  k_main<<<dim3(NB, 2), 512, 0, stream>>>(partial, wb, xb16,
                                          g_max, b_max, m_max, v_max,
                                          g_med, b_med, m_med, v_med, out);
}